// Round 1
// baseline (410.228 us; speedup 1.0000x reference)
//
#include <hip/hip_runtime.h>

#define TEN 10

// ---------------------------------------------------------------------------
// Phase A: each 10-lane group computes the ordered product of L per-step
// transition matrices W_t = sum_k x[t,k] * P[k] for its chunk.
// Lane r of a group owns row r of the chunk accumulator M and the P-slice
// P[:, r, :] in registers. W is shared within the group via LDS each step.
// ---------------------------------------------------------------------------
__global__ __launch_bounds__(256, 1) void automaton_chunks(
    const float* __restrict__ x, const float* __restrict__ P,
    float* __restrict__ outM, int C, int L)
{
    // 4 waves/block * 6 groups/wave * 10 rows * 12 floats (padded) = 11.25 KB
    __shared__ __align__(16) float wlds[4][6][TEN][12];

    const int tid  = threadIdx.x;
    const int wave = tid >> 6;
    const int lane = tid & 63;
    const int g    = lane / TEN;   // group within wave (0..5; 6 = idle lanes)
    const int r    = lane % TEN;   // row owned by this lane
    const int chunk = blockIdx.x * 24 + wave * 6 + g;
    if (g >= 6 || chunk >= C) return;

    // Loop-invariant P slice: p[k][j] = P[k][r][j]  (100 VGPRs)
    float p[TEN][TEN];
#pragma unroll
    for (int k = 0; k < TEN; ++k)
#pragma unroll
        for (int j = 0; j < TEN; ++j)
            p[k][j] = P[k * 100 + r * TEN + j];

    // M starts as identity; lane holds row r.
    float m[TEN];
#pragma unroll
    for (int j = 0; j < TEN; ++j) m[j] = (j == r) ? 1.0f : 0.0f;

    // x rows are 10 floats = 40 B -> only 8 B aligned, so float2 loads.
    const float2* xp = reinterpret_cast<const float2*>(x) + (size_t)chunk * L * 5;
    float* wrow      = &wlds[wave][g][r][0];
    const float* wg  = &wlds[wave][g][0][0];

    // Prefetch first x row.
    float2 nx0 = xp[0], nx1 = xp[1], nx2 = xp[2], nx3 = xp[3], nx4 = xp[4];
    xp += 5;

    for (int s = 0; s < L; ++s) {
        const float xv[TEN] = {nx0.x, nx0.y, nx1.x, nx1.y, nx2.x,
                               nx2.y, nx3.x, nx3.y, nx4.x, nx4.y};
        // Prefetch next x row before the LDS ordering barrier (vmcnt untouched).
        if (s + 1 < L) {
            nx0 = xp[0]; nx1 = xp[1]; nx2 = xp[2]; nx3 = xp[3]; nx4 = xp[4];
            xp += 5;
        }
        // Build W row r: w[j] = sum_k x[k] * P[k][r][j]   (100 FMA)
        float w[TEN];
#pragma unroll
        for (int j = 0; j < TEN; ++j) {
            float acc = xv[0] * p[0][j];
#pragma unroll
            for (int k = 1; k < TEN; ++k) acc = fmaf(xv[k], p[k][j], acc);
            w[j] = acc;
        }
        // Publish row to LDS (rows padded to 12 floats; 48B stride keeps 16B align).
        reinterpret_cast<float4*>(wrow)[0]     = make_float4(w[0], w[1], w[2], w[3]);
        reinterpret_cast<float4*>(wrow)[1]     = make_float4(w[4], w[5], w[6], w[7]);
        reinterpret_cast<float2*>(wrow + 8)[0] = make_float2(w[8], w[9]);
        // Same-wave LDS write->read: DS ops are in-order per wave; the waitcnt
        // guarantees commit and the memory clobber pins compiler ordering.
        asm volatile("s_waitcnt lgkmcnt(0)" ::: "memory");

        // M row update: mn[j] = sum_a m[a] * W[a][j]   (100 FMA)
        float mn[TEN] = {0, 0, 0, 0, 0, 0, 0, 0, 0, 0};
#pragma unroll
        for (int a = 0; a < TEN; ++a) {
            const float4 wa0 = reinterpret_cast<const float4*>(wg + a * 12)[0];
            const float4 wa1 = reinterpret_cast<const float4*>(wg + a * 12)[1];
            const float2 wa2 = reinterpret_cast<const float2*>(wg + a * 12 + 8)[0];
            const float ma = m[a];
            mn[0] = fmaf(ma, wa0.x, mn[0]);
            mn[1] = fmaf(ma, wa0.y, mn[1]);
            mn[2] = fmaf(ma, wa0.z, mn[2]);
            mn[3] = fmaf(ma, wa0.w, mn[3]);
            mn[4] = fmaf(ma, wa1.x, mn[4]);
            mn[5] = fmaf(ma, wa1.y, mn[5]);
            mn[6] = fmaf(ma, wa1.z, mn[6]);
            mn[7] = fmaf(ma, wa1.w, mn[7]);
            mn[8] = fmaf(ma, wa2.x, mn[8]);
            mn[9] = fmaf(ma, wa2.y, mn[9]);
        }
#pragma unroll
        for (int j = 0; j < TEN; ++j) m[j] = mn[j];
        // Keep next iteration's writes from being hoisted above these reads.
        asm volatile("s_waitcnt lgkmcnt(0)" ::: "memory");
    }

    float* dst = outM + (size_t)chunk * 100 + r * TEN;
#pragma unroll
    for (int j = 0; j < TEN; ++j) dst[j] = m[j];
}

// ---------------------------------------------------------------------------
// Reduction: group g multiplies R consecutive matrices (in order) into one.
// ---------------------------------------------------------------------------
__device__ __forceinline__ float bel(const float4* b, int i)
{
    const float4 v = b[i >> 2];
    switch (i & 3) {
        case 0: return v.x;
        case 1: return v.y;
        case 2: return v.z;
        default: return v.w;
    }
}

__global__ void reduce_chain(const float* __restrict__ in, float* __restrict__ out,
                             int nOut, int R)
{
    const int tid  = threadIdx.x;
    const int wave = tid >> 6;
    const int lane = tid & 63;
    const int g    = lane / TEN;
    const int r    = lane % TEN;
    const int gpb  = (blockDim.x >> 6) * 6;
    const int grp  = blockIdx.x * gpb + wave * 6 + g;
    if (g >= 6 || grp >= nOut) return;

    const float* base = in + (size_t)grp * R * 100;
    float a[TEN];
#pragma unroll
    for (int j = 0; j < TEN; ++j) a[j] = base[r * TEN + j];

    for (int mm = 1; mm < R; ++mm) {
        const float4* b4 = reinterpret_cast<const float4*>(base + mm * 100);
        float4 b[25];
#pragma unroll
        for (int q = 0; q < 25; ++q) b[q] = b4[q];
        float an[TEN] = {0, 0, 0, 0, 0, 0, 0, 0, 0, 0};
#pragma unroll
        for (int aa = 0; aa < TEN; ++aa) {
            const float ma = a[aa];
#pragma unroll
            for (int j = 0; j < TEN; ++j)
                an[j] = fmaf(ma, bel(b, aa * TEN + j), an[j]);
        }
#pragma unroll
        for (int j = 0; j < TEN; ++j) a[j] = an[j];
    }
    float* dst = out + (size_t)grp * 100 + r * TEN;
#pragma unroll
    for (int j = 0; j < TEN; ++j) dst[j] = a[j];
}

// ---------------------------------------------------------------------------
// Finalize: multiply the last n matrices, apply start_state and accept_states.
// ---------------------------------------------------------------------------
__global__ void finalize(const float* __restrict__ in, int n,
                         const float* __restrict__ start, const float* __restrict__ acc,
                         float* __restrict__ outv)
{
    __shared__ float sred[TEN][12];
    const int lane = threadIdx.x;

    if (lane < TEN) {
        const int r = lane;
        float a[TEN];
#pragma unroll
        for (int j = 0; j < TEN; ++j) a[j] = in[r * TEN + j];
        for (int mm = 1; mm < n; ++mm) {
            const float4* b4 = reinterpret_cast<const float4*>(in + mm * 100);
            float4 b[25];
#pragma unroll
            for (int q = 0; q < 25; ++q) b[q] = b4[q];
            float an[TEN] = {0, 0, 0, 0, 0, 0, 0, 0, 0, 0};
#pragma unroll
            for (int aa = 0; aa < TEN; ++aa) {
                const float ma = a[aa];
#pragma unroll
                for (int j = 0; j < TEN; ++j)
                    an[j] = fmaf(ma, bel(b, aa * TEN + j), an[j]);
            }
#pragma unroll
            for (int j = 0; j < TEN; ++j) a[j] = an[j];
        }
        const float sr = start[r];
#pragma unroll
        for (int j = 0; j < TEN; ++j) sred[r][j] = sr * a[j];
    }
    __syncthreads();
    if (lane == 0) {
        float o0 = 0.0f, o1 = 0.0f;
#pragma unroll
        for (int j = 0; j < TEN; ++j) {
            float t = 0.0f;
#pragma unroll
            for (int rr = 0; rr < TEN; ++rr) t += sred[rr][j];
            o0 = fmaf(t, acc[j * 2 + 0], o0);
            o1 = fmaf(t, acc[j * 2 + 1], o1);
        }
        outv[0] = o0;
        outv[1] = o1;
    }
}

extern "C" void kernel_launch(void* const* d_in, const int* in_sizes, int n_in,
                              void* d_out, int out_size, void* d_ws, size_t ws_size,
                              hipStream_t stream)
{
    const float* x     = (const float*)d_in[0];
    const float* P     = (const float*)d_in[1];
    const float* start = (const float*)d_in[2];
    const float* acc   = (const float*)d_in[3];
    float* out         = (float*)d_out;

    const long long T = (long long)in_sizes[0] / TEN;  // 2,097,152 steps

    // Workspace: C chunk matrices + 512 level-1 matrices + 8 level-2 matrices,
    // each 100 floats. Pick C to fit ws_size (same choice every call).
    long long C = 2048;
    if (ws_size >= (size_t)(16384 + 512 + 8) * 400)      C = 16384;
    else if (ws_size >= (size_t)(8192 + 512 + 8) * 400)  C = 8192;
    else if (ws_size >= (size_t)(4096 + 512 + 8) * 400)  C = 4096;
    const int L  = (int)(T / C);       // steps per chunk (T is a power of two)
    const int R1 = (int)(C / 512);     // level-1 radix

    float* ws1 = (float*)d_ws;                    // [C][10][10]
    float* ws2 = ws1 + (size_t)C * 100;           // [512][10][10]
    float* ws3 = ws2 + (size_t)512 * 100;         // [8][10][10]

    automaton_chunks<<<(int)((C + 23) / 24), 256, 0, stream>>>(x, P, ws1, (int)C, L);
    reduce_chain<<<(512 + 23) / 24, 256, 0, stream>>>(ws1, ws2, 512, R1);   // C -> 512
    reduce_chain<<<1, 128, 0, stream>>>(ws2, ws3, 8, 64);                   // 512 -> 8
    finalize<<<1, 64, 0, stream>>>(ws3, 8, start, acc, out);
}